// Round 8
// baseline (323.063 us; speedup 1.0000x reference)
//
#include <hip/hip_runtime.h>
#include <cmath>

// INGP hashgrid encode — R13: XCD-local sort + split-fused gather (R12).
//   Budget decomposition (solved across R0-R12): fixed harness OH ~72us
//   (unattackable), fine 102 (AT per-XCD L2-lookup floor: 3.1M lookups/XCD
//   @31G/s), finish ~76, sort chain ~61 for 3 passes over 8MB (~15 ideal).
//   Sort excess = 2x 524K device-scope atomics on a shared 128KB bin region:
//   ~87% hit lines cached in a FOREIGN XCD's L2 -> coherence migration per
//   atomic (R10's store-packing null already exonerated the stores).
//   R13: partition by block id (b&7 ~ XCD):
//     - hist8[8][NBINS] planes: plane-k touched only by blocks b%8==k ->
//       atomic lines stay exclusive to one L2, no migration.
//     - scan8: 8 independent per-plane scans (8 concurrent blocks, same
//       verified scan body).
//     - scatter8: plane-local atomics + stores into XCD-SEGMENTED staging
//       (region k written only by plane-k blocks -> exclusive lines).
//     - merge: one wave per bin pulls the 8 staged sub-segments into final
//       bin-major pts4; writes are single-wave coalesced full lines; reads
//       are read-only (no coherence cost). base(b) = sum_x off_local[x][b],
//       off_local = bumped - hist (no extra copies needed).
//   fine/finish identical to R12 (proven): fine = levels 8-15 XCD-pinned
//   level-major -> ws[8][N]; finish = coarse 0-7 in-register (sorted
//   locality) + LDS assemble + full 128B single-owner rows at orig index.

constexpr int LVLS = 16;
constexpr unsigned TBL = 1u << 19;
constexpr unsigned TMASK = TBL - 1u;
constexpr unsigned P1 = 2654435761u;
constexpr unsigned P2 = 805459861u;
constexpr int PTS_PER_BLOCK = 512;   // fine kernel: 256 threads x 2 points
constexpr int NBINS = 32768;         // 32^3 Morton bins

typedef float vf2 __attribute__((ext_vector_type(2)));
typedef float vf4 __attribute__((ext_vector_type(4)));

struct ResArr { float r[LVLS]; };
struct XB { int base[8]; };          // staging region bases (vf4 units)

__device__ __forceinline__ unsigned spread5(unsigned v) {
    v &= 31u;
    v = (v | (v << 8)) & 0x100Fu;
    v = (v | (v << 4)) & 0x10C3u;
    v = (v | (v << 2)) & 0x1249u;
    return v;
}

__device__ __forceinline__ unsigned bin_key(float px, float py, float pz) {
    float x = (px + 1.0f) * 0.5f;
    float y = (py + 1.0f) * 0.5f;
    float z = (pz + 1.0f) * 0.5f;
    unsigned bx = (unsigned)fminf(31.f, fmaxf(0.f, floorf(x * 32.f)));
    unsigned by = (unsigned)fminf(31.f, fmaxf(0.f, floorf(y * 32.f)));
    unsigned bz = (unsigned)fminf(31.f, fmaxf(0.f, floorf(z * 32.f)));
    return spread5(bx) | (spread5(by) << 1) | (spread5(bz) << 2);
}

// One level's trilinear hashed gather for normalized point (x,y,z).
__device__ __forceinline__ void level_gather(
    const float2* __restrict__ tab, float r,
    float x, float y, float z, float& f0, float& f1)
{
    float posx = x * r, posy = y * r, posz = z * r;
    float fx = floorf(posx), fy = floorf(posy), fz = floorf(posz);
    float wx = posx - fx, wy = posy - fy, wz = posz - fz;
    unsigned ix = (unsigned)fx, iy = (unsigned)fy, iz = (unsigned)fz;
    unsigned hx0 = ix, hx1 = ix + 1u;
    unsigned hy0 = iy * P1;
    unsigned hz0 = iz * P2, hz1 = hz0 + P2;

    unsigned hyz[4];
    hyz[0] = hy0 ^ hz0;
    hyz[1] = hy0 ^ hz1;
    hyz[2] = (hy0 + P1) ^ hz0;
    hyz[3] = (hy0 + P1) ^ hz1;

    float2 v[8];
    if ((ix & 1u) == 0u) {
        // x-pair idx differ by ^1 -> one aligned float4 covers both.
        #pragma unroll
        for (int yz = 0; yz < 4; ++yz) {
            unsigned b0 = (hx0 ^ hyz[yz]) & TMASK;   // x=0 corner
            vf4 qd = *(const vf4*)(tab + (b0 & ~1u));
            float2 lo = make_float2(qd.x, qd.y);
            float2 hi = make_float2(qd.z, qd.w);
            bool odd = (b0 & 1u) != 0u;
            v[yz]     = odd ? hi : lo;
            v[4 + yz] = odd ? lo : hi;
        }
    } else {
        #pragma unroll
        for (int yz = 0; yz < 4; ++yz) {
            unsigned b0 = (hx0 ^ hyz[yz]) & TMASK;
            unsigned b1 = (hx1 ^ hyz[yz]) & TMASK;
            v[yz]     = tab[b0];
            v[4 + yz] = tab[b1];
        }
    }

    float ox = 1.0f - wx, oy = 1.0f - wy, oz = 1.0f - wz;
    float w[8];
    w[0] = (ox * oy) * oz;
    w[1] = (ox * oy) * wz;
    w[2] = (ox * wy) * oz;
    w[3] = (ox * wy) * wz;
    w[4] = (wx * oy) * oz;
    w[5] = (wx * oy) * wz;
    w[6] = (wx * wy) * oz;
    w[7] = (wx * wy) * wz;

    f0 = w[0] * v[0].x;
    f1 = w[0] * v[0].y;
    #pragma unroll
    for (int c = 1; c < 8; ++c) {
        f0 += w[c] * v[c].x;
        f1 += w[c] * v[c].y;
    }
}

// hist8[plane][bin], plane = blockIdx%8 -> atomics stay XCD-local.
__global__ __launch_bounds__(256) void ingp_hist8(
    const float* __restrict__ pts, unsigned* __restrict__ hist8, int npts)
{
    int i = blockIdx.x * 256 + threadIdx.x;
    if (i >= npts) return;
    int plane = blockIdx.x & 7;
    float px = pts[i * 3 + 0], py = pts[i * 3 + 1], pz = pts[i * 3 + 2];
    atomicAdd(&hist8[plane * NBINS + bin_key(px, py, pz)], 1u);
}

// 8 independent per-plane exclusive scans; blockIdx = plane.
__global__ __launch_bounds__(1024) void ingp_scan8(
    const unsigned* __restrict__ hist8, unsigned* __restrict__ off)
{
    __shared__ unsigned sc[1024];
    int plane = blockIdx.x;
    const unsigned* h = hist8 + (size_t)plane * NBINS;
    unsigned* o = off + (size_t)plane * NBINS;
    int t = threadIdx.x;
    unsigned loc[32];
    unsigned s = 0;
    #pragma unroll
    for (int i = 0; i < 32; ++i) { loc[i] = s; s += h[t * 32 + i]; }
    sc[t] = s;
    __syncthreads();
    for (int d = 1; d < 1024; d <<= 1) {
        unsigned v = (t >= d) ? sc[t - d] : 0u;
        __syncthreads();
        sc[t] += v;
        __syncthreads();
    }
    unsigned base = sc[t] - s;   // exclusive prefix of this thread's chunk
    #pragma unroll
    for (int i = 0; i < 32; ++i) o[t * 32 + i] = base + loc[i];
}

// Scatter into XCD-segmented staging: plane-k blocks write only region k.
__global__ __launch_bounds__(256) void ingp_scatter8(
    const float* __restrict__ pts, unsigned* __restrict__ off,
    vf4* __restrict__ stage, XB xb, int npts)
{
    int i = blockIdx.x * 256 + threadIdx.x;
    if (i >= npts) return;
    int plane = blockIdx.x & 7;
    float px = pts[i * 3 + 0], py = pts[i * 3 + 1], pz = pts[i * 3 + 2];
    unsigned bin = bin_key(px, py, pz);
    unsigned pos = atomicAdd(&off[plane * NBINS + bin], 1u);
    vf4 o; o.x = px; o.y = py; o.z = pz; o.w = __int_as_float(i);
    __builtin_nontemporal_store(o, stage + xb.base[plane] + pos);
}

// Merge 8 staged sub-segments per bin into final bin-major pts4.
// One wave per bin; writes single-wave coalesced full lines.
__global__ __launch_bounds__(256) void ingp_merge(
    const vf4* __restrict__ stage,
    const unsigned* __restrict__ hist8,
    const unsigned* __restrict__ off,   // post-scatter (bumped)
    XB xb, vf4* __restrict__ pts4)
{
    int t = threadIdx.x;
    int bin = blockIdx.x * 4 + (t >> 6);
    int lane = t & 63;

    unsigned h[8], s[8], cum[9];
    unsigned base = 0;
    cum[0] = 0;
    #pragma unroll
    for (int x = 0; x < 8; ++x) {
        unsigned hx = hist8[x * NBINS + bin];
        unsigned sx = off[x * NBINS + bin] - hx;  // off_local (scan output)
        h[x] = hx; s[x] = sx;
        base += sx;                               // sum_x off_local = bin start
        cum[x + 1] = cum[x] + hx;
    }
    unsigned total = cum[8];

    for (unsigned l = lane; l < total; l += 64) {
        int x = 0;
        while (l >= cum[x + 1]) ++x;              // <=8 steps
        vf4 v = __builtin_nontemporal_load(
            stage + xb.base[x] + s[x] + (l - cum[x]));
        pts4[base + l] = v;
    }
}

// A: fine levels 8-15, level-major, XCD-pinned; ws[lvl-8][N] coalesced.
__global__ __launch_bounds__(256) void ingp_fine(
    const vf4* __restrict__ pts4,
    const float* __restrict__ tables,
    float2* __restrict__ ws,          // [8][N] float2
    ResArr ra, int npts)
{
    int b = blockIdx.x;
    int lvl = 8 + (b & 7);            // XCD-pinned: blockIdx%8 -> XCD
    int q = b >> 3;
    int t = threadIdx.x;

    float r = ra.r[lvl];
    const float2* __restrict__ tab = (const float2*)tables + (size_t)lvl * TBL;
    float2* __restrict__ wrow = ws + (size_t)(lvl - 8) * npts;

    #pragma unroll
    for (int s = 0; s < 2; ++s) {
        int p = q * PTS_PER_BLOCK + t + s * 256;
        bool valid = p < npts;
        int pp = valid ? p : 0;
        vf4 v = pts4[pp];
        float x = (v.x + 1.0f) * 0.5f;
        float y = (v.y + 1.0f) * 0.5f;
        float z = (v.z + 1.0f) * 0.5f;
        float f0, f1;
        level_gather(tab, r, x, y, z, f0, f1);
        if (valid) {
            vf2 o; o.x = f0; o.y = f1;
            __builtin_nontemporal_store(o, (vf2*)(wrow + p));
        }
    }
}

// B: coarse levels 0-7 in registers + fine rows from ws; LDS assemble;
// full 128B single-owner rows at original index (8 lanes per row).
__global__ __launch_bounds__(256) void ingp_finish(
    const vf4* __restrict__ pts4,
    const float* __restrict__ tables,
    const float2* __restrict__ ws,    // [8][N] float2
    vf4* __restrict__ out,            // [N][8] vf4 rows (original order)
    ResArr ra, int npts)
{
    __shared__ float2 a[LVLS][258];
    __shared__ int s_orig[256];
    int base = blockIdx.x * 256;
    int t = threadIdx.x;
    int p = base + t;
    bool valid = p < npts;
    int pp = valid ? p : 0;

    vf4 v4 = pts4[pp];
    s_orig[t] = __float_as_int(v4.w);
    float x = (v4.x + 1.0f) * 0.5f;
    float y = (v4.y + 1.0f) * 0.5f;
    float z = (v4.z + 1.0f) * 0.5f;

    #pragma unroll
    for (int l = 0; l < 8; ++l) {
        const float2* __restrict__ tab = (const float2*)tables + (size_t)l * TBL;
        float f0, f1;
        level_gather(tab, ra.r[l], x, y, z, f0, f1);
        a[l][t] = make_float2(f0, f1);
    }
    #pragma unroll
    for (int l = 8; l < LVLS; ++l) {
        vf2 w = __builtin_nontemporal_load(
            (const vf2*)(ws + (size_t)(l - 8) * npts + pp));
        a[l][t] = make_float2(w.x, w.y);
    }
    __syncthreads();

    int j = t & 7;
    int pl = t >> 3;
    #pragma unroll
    for (int it = 0; it < 8; ++it) {
        int pt = pl + it * 32;
        if (base + pt < npts) {
            int orig = s_orig[pt];
            float2 u = a[2 * j][pt];
            float2 v = a[2 * j + 1][pt];
            vf4 o; o.x = u.x; o.y = u.y; o.z = v.x; o.w = v.y;
            __builtin_nontemporal_store(o, (vf4*)(out + (size_t)orig * 8 + j));
        }
    }
}

// Fallback (no usable ws): unsorted single-kernel path.
__global__ __launch_bounds__(256) void ingp_fused_raw(
    const float* __restrict__ pts,
    const float* __restrict__ tables,
    vf4* __restrict__ out, ResArr ra, int npts)
{
    int i = blockIdx.x * 256 + threadIdx.x;
    bool valid = i < npts;
    int pp = valid ? i : 0;
    float x = (pts[pp * 3 + 0] + 1.0f) * 0.5f;
    float y = (pts[pp * 3 + 1] + 1.0f) * 0.5f;
    float z = (pts[pp * 3 + 2] + 1.0f) * 0.5f;

    float acc[2 * LVLS];
    #pragma unroll
    for (int l = 0; l < LVLS; ++l) {
        const float2* __restrict__ tab = (const float2*)tables + (size_t)l * TBL;
        float f0, f1;
        level_gather(tab, ra.r[l], x, y, z, f0, f1);
        acc[2 * l] = f0; acc[2 * l + 1] = f1;
    }
    if (valid) {
        vf4* row = out + (size_t)pp * 8;
        #pragma unroll
        for (int k = 0; k < 8; ++k) {
            vf4 o;
            o.x = acc[4 * k + 0]; o.y = acc[4 * k + 1];
            o.z = acc[4 * k + 2]; o.w = acc[4 * k + 3];
            __builtin_nontemporal_store(o, row + k);
        }
    }
}

extern "C" void kernel_launch(void* const* d_in, const int* in_sizes, int n_in,
                              void* d_out, int out_size, void* d_ws, size_t ws_size,
                              hipStream_t stream) {
    const float* pts    = (const float*)d_in[0];
    const float* tables = (const float*)d_in[1];
    int npts = in_sizes[0] / 3;

    // numpy-bitwise RES: GROWTH = exp((log(2048)-log(16))/15); floor(16*G**l)
    ResArr ra;
    double growth = exp((log(2048.0) - log(16.0)) / 15.0);
    for (int l = 0; l < LVLS; ++l)
        ra.r[l] = (float)floor(16.0 * pow(growth, (double)l));

    int pgrid = (npts + 255) / 256;
    int bpl = (npts + PTS_PER_BLOCK - 1) / PTS_PER_BLOCK;

    // Exact per-plane point counts (block-id partition, data-independent).
    long cnt[8] = {0,0,0,0,0,0,0,0};
    for (int b = 0; b < pgrid; ++b) {
        int n = npts - b * 256; if (n > 256) n = 256;
        cnt[b & 7] += n;
    }
    XB xb; long cum = 0;
    for (int k = 0; k < 8; ++k) {
        xb.base[k] = (int)cum;
        cum += (cnt[k] + 3) & ~3L;    // pad each region to 64B lines
    }

    // ws layout: [fine ws: 8*N f2][pts4: N vf4][stage: cum vf4][hist8][off]
    size_t fine_bytes  = 8ull * npts * sizeof(float2);
    size_t pts4_bytes  = (size_t)npts * sizeof(vf4);
    size_t stage_bytes = (size_t)cum * sizeof(vf4);
    size_t hist_bytes  = 8ull * NBINS * sizeof(unsigned);
    size_t need = fine_bytes + pts4_bytes + stage_bytes + 2 * hist_bytes;

    if (ws_size >= need) {
        char* w = (char*)d_ws;
        float2*   wsf   = (float2*)w;                 w += fine_bytes;
        vf4*      pts4  = (vf4*)w;                    w += pts4_bytes;
        vf4*      stage = (vf4*)w;                    w += stage_bytes;
        unsigned* hist8 = (unsigned*)w;               w += hist_bytes;
        unsigned* off   = (unsigned*)w;

        hipMemsetAsync(hist8, 0, hist_bytes, stream);
        hipLaunchKernelGGL(ingp_hist8, dim3(pgrid), dim3(256), 0, stream,
                           pts, hist8, npts);
        hipLaunchKernelGGL(ingp_scan8, dim3(8), dim3(1024), 0, stream,
                           hist8, off);
        hipLaunchKernelGGL(ingp_scatter8, dim3(pgrid), dim3(256), 0, stream,
                           pts, off, stage, xb, npts);
        hipLaunchKernelGGL(ingp_merge, dim3(NBINS / 4), dim3(256), 0, stream,
                           stage, hist8, off, xb, pts4);
        hipLaunchKernelGGL(ingp_fine, dim3(8 * bpl), dim3(256), 0, stream,
                           pts4, tables, wsf, ra, npts);
        hipLaunchKernelGGL(ingp_finish, dim3(pgrid), dim3(256), 0, stream,
                           pts4, tables, wsf, (vf4*)d_out, ra, npts);
    } else {
        hipLaunchKernelGGL(ingp_fused_raw, dim3(pgrid), dim3(256), 0, stream,
                           pts, tables, (vf4*)d_out, ra, npts);
    }
}

// Round 9
// 309.270 us; speedup vs baseline: 1.0446x; 1.0446x over previous
//
#include <hip/hip_runtime.h>
#include <cmath>

// INGP hashgrid encode — R14: single-pass slotted Morton binning + R12's
// proven split-fused gather.
//   Validated ledger: fine (levels 8-15, XCD-pinned level-major) = 102us,
//   AT the per-XCD L2 lookup floor (3.1M lookups/XCD @ ~31G/s). finish
//   (coarse 0-7 in-register on Morton-local points + LDS row assemble,
//   full 128B single-owner rows) = ~76us. R13 disproved the cross-XCD
//   atomic-migration theory (plane-local atomics gained ~4us, merge cost
//   more). Sort-chain time is ~2/3 DISPATCH GAP (~10-13us/boundary;
//   work only ~22us) -> the lever is deleting dispatches.
//   R14: replace hist+scan+scatter counting sort with ONE scatter pass
//   into fixed-capacity Morton bins:
//     slots[NBINS][CAP=24] (lambda=16/bin) + overflow[OVCAP=64K] tail;
//     pos = atomicAdd(cnt[bin]): pos<CAP -> slot; else overflow; else
//     (adversarial only) full 16-level encode INLINE -> correct for any
//     input. Slot array is Morton-ordered by construction; fine/finish
//     scan it linearly, masking invalid slots via cnt (L1-hot broadcast;
//     invalid lanes issue NO table lookups -> lookup-bound time intact).
//   Dispatches 6 -> 4 (memset, scatter1, fine, finish): deletes hist
//   (~18us) and scan (~13us) including their gaps.

constexpr int LVLS = 16;
constexpr unsigned TBL = 1u << 19;
constexpr unsigned TMASK = TBL - 1u;
constexpr unsigned P1 = 2654435761u;
constexpr unsigned P2 = 805459861u;
constexpr int NBINS = 32768;         // 32^3 Morton bins
constexpr int CAP = 24;              // slots per bin (Poisson mean 16)
constexpr int MAIN = NBINS * CAP;    // 786432 main slots
constexpr int OVCAP = 65536;         // overflow slots
constexpr int S_TOT = MAIN + OVCAP;  // 851968 = 512*1664 = 256*3328
constexpr int SLOTS_PER_FINE_BLOCK = 512;

typedef float vf2 __attribute__((ext_vector_type(2)));
typedef float vf4 __attribute__((ext_vector_type(4)));

struct ResArr { float r[LVLS]; };

__device__ __forceinline__ unsigned spread5(unsigned v) {
    v &= 31u;
    v = (v | (v << 8)) & 0x100Fu;
    v = (v | (v << 4)) & 0x10C3u;
    v = (v | (v << 2)) & 0x1249u;
    return v;
}

__device__ __forceinline__ unsigned bin_key(float px, float py, float pz) {
    float x = (px + 1.0f) * 0.5f;
    float y = (py + 1.0f) * 0.5f;
    float z = (pz + 1.0f) * 0.5f;
    unsigned bx = (unsigned)fminf(31.f, fmaxf(0.f, floorf(x * 32.f)));
    unsigned by = (unsigned)fminf(31.f, fmaxf(0.f, floorf(y * 32.f)));
    unsigned bz = (unsigned)fminf(31.f, fmaxf(0.f, floorf(z * 32.f)));
    return spread5(bx) | (spread5(by) << 1) | (spread5(bz) << 2);
}

// One level's trilinear hashed gather for normalized point (x,y,z).
__device__ __forceinline__ void level_gather(
    const float2* __restrict__ tab, float r,
    float x, float y, float z, float& f0, float& f1)
{
    float posx = x * r, posy = y * r, posz = z * r;
    float fx = floorf(posx), fy = floorf(posy), fz = floorf(posz);
    float wx = posx - fx, wy = posy - fy, wz = posz - fz;
    unsigned ix = (unsigned)fx, iy = (unsigned)fy, iz = (unsigned)fz;
    unsigned hx0 = ix, hx1 = ix + 1u;
    unsigned hy0 = iy * P1;
    unsigned hz0 = iz * P2, hz1 = hz0 + P2;

    unsigned hyz[4];
    hyz[0] = hy0 ^ hz0;
    hyz[1] = hy0 ^ hz1;
    hyz[2] = (hy0 + P1) ^ hz0;
    hyz[3] = (hy0 + P1) ^ hz1;

    float2 v[8];
    if ((ix & 1u) == 0u) {
        // x-pair idx differ by ^1 -> one aligned float4 covers both.
        #pragma unroll
        for (int yz = 0; yz < 4; ++yz) {
            unsigned b0 = (hx0 ^ hyz[yz]) & TMASK;   // x=0 corner
            vf4 qd = *(const vf4*)(tab + (b0 & ~1u));
            float2 lo = make_float2(qd.x, qd.y);
            float2 hi = make_float2(qd.z, qd.w);
            bool odd = (b0 & 1u) != 0u;
            v[yz]     = odd ? hi : lo;
            v[4 + yz] = odd ? lo : hi;
        }
    } else {
        #pragma unroll
        for (int yz = 0; yz < 4; ++yz) {
            unsigned b0 = (hx0 ^ hyz[yz]) & TMASK;
            unsigned b1 = (hx1 ^ hyz[yz]) & TMASK;
            v[yz]     = tab[b0];
            v[4 + yz] = tab[b1];
        }
    }

    float ox = 1.0f - wx, oy = 1.0f - wy, oz = 1.0f - wz;
    float w[8];
    w[0] = (ox * oy) * oz;
    w[1] = (ox * oy) * wz;
    w[2] = (ox * wy) * oz;
    w[3] = (ox * wy) * wz;
    w[4] = (wx * oy) * oz;
    w[5] = (wx * oy) * wz;
    w[6] = (wx * wy) * oz;
    w[7] = (wx * wy) * wz;

    f0 = w[0] * v[0].x;
    f1 = w[0] * v[0].y;
    #pragma unroll
    for (int c = 1; c < 8; ++c) {
        f0 += w[c] * v[c].x;
        f1 += w[c] * v[c].y;
    }
}

// Full 16-level encode for one point, row written directly (rare paths).
__device__ __forceinline__ void encode_point_direct(
    const float* __restrict__ tables, const ResArr& ra,
    float px, float py, float pz, vf4* __restrict__ row)
{
    float x = (px + 1.0f) * 0.5f;
    float y = (py + 1.0f) * 0.5f;
    float z = (pz + 1.0f) * 0.5f;
    float acc[2 * LVLS];
    #pragma unroll
    for (int l = 0; l < LVLS; ++l) {
        const float2* __restrict__ tab = (const float2*)tables + (size_t)l * TBL;
        float f0, f1;
        level_gather(tab, ra.r[l], x, y, z, f0, f1);
        acc[2 * l] = f0; acc[2 * l + 1] = f1;
    }
    #pragma unroll
    for (int k = 0; k < 8; ++k) {
        vf4 o;
        o.x = acc[4 * k + 0]; o.y = acc[4 * k + 1];
        o.z = acc[4 * k + 2]; o.w = acc[4 * k + 3];
        __builtin_nontemporal_store(o, row + k);
    }
}

// Single-pass slotted scatter. cnt[NBINS] = per-bin counters, cnt[NBINS]
// (last entry) = overflow counter. Every point lands in exactly one of:
// main slot / overflow slot / inline-encoded output row.
__global__ __launch_bounds__(256) void ingp_scatter1(
    const float* __restrict__ pts, unsigned* __restrict__ cnt,
    vf4* __restrict__ slots, const float* __restrict__ tables,
    vf4* __restrict__ out, ResArr ra, int npts)
{
    int i = blockIdx.x * 256 + threadIdx.x;
    if (i >= npts) return;
    float px = pts[i * 3 + 0], py = pts[i * 3 + 1], pz = pts[i * 3 + 2];
    unsigned bin = bin_key(px, py, pz);
    unsigned pos = atomicAdd(&cnt[bin], 1u);
    vf4 o; o.x = px; o.y = py; o.z = pz; o.w = __int_as_float(i);
    if (pos < (unsigned)CAP) {
        __builtin_nontemporal_store(o, slots + (size_t)bin * CAP + pos);
    } else {
        unsigned ov = atomicAdd(&cnt[NBINS], 1u);
        if (ov < (unsigned)OVCAP) {
            __builtin_nontemporal_store(o, slots + MAIN + ov);
        } else {
            // adversarial-only fallback: encode inline, still correct
            encode_point_direct(tables, ra, px, py, pz,
                                out + (size_t)i * 8);
        }
    }
}

// Slot validity: main slot s -> within < min(cnt[bin],CAP);
// overflow slot -> idx < min(cnt[NBINS],OVCAP).
__device__ __forceinline__ bool slot_valid(
    const unsigned* __restrict__ cnt, int sidx)
{
    if (sidx < MAIN) {
        unsigned bin = (unsigned)sidx / (unsigned)CAP;
        unsigned within = (unsigned)sidx - bin * (unsigned)CAP;
        unsigned c = cnt[bin];
        return within < (c < (unsigned)CAP ? c : (unsigned)CAP);
    } else {
        unsigned idx = (unsigned)(sidx - MAIN);
        unsigned c = cnt[NBINS];
        return idx < (c < (unsigned)OVCAP ? c : (unsigned)OVCAP);
    }
}

// A: fine levels 8-15, level-major, XCD-pinned; ws[lvl-8][S_TOT] coalesced.
// Invalid slots issue no lookups (lookup-throughput preserved).
__global__ __launch_bounds__(256) void ingp_fine(
    const vf4* __restrict__ slots, const unsigned* __restrict__ cnt,
    const float* __restrict__ tables,
    float2* __restrict__ ws,          // [8][S_TOT] float2
    ResArr ra)
{
    int b = blockIdx.x;
    int lvl = 8 + (b & 7);            // XCD-pinned: blockIdx%8 -> XCD
    int q = b >> 3;
    int t = threadIdx.x;

    float r = ra.r[lvl];
    const float2* __restrict__ tab = (const float2*)tables + (size_t)lvl * TBL;
    float2* __restrict__ wrow = ws + (size_t)(lvl - 8) * S_TOT;

    #pragma unroll
    for (int s = 0; s < 2; ++s) {
        int sidx = q * SLOTS_PER_FINE_BLOCK + t + s * 256;   // < S_TOT exact
        if (!slot_valid(cnt, sidx)) continue;
        vf4 v = slots[sidx];
        float x = (v.x + 1.0f) * 0.5f;
        float y = (v.y + 1.0f) * 0.5f;
        float z = (v.z + 1.0f) * 0.5f;
        float f0, f1;
        level_gather(tab, r, x, y, z, f0, f1);
        vf2 o; o.x = f0; o.y = f1;
        __builtin_nontemporal_store(o, (vf2*)(wrow + sidx));
    }
}

// B: coarse levels 0-7 in registers (slots are Morton-local) + fine rows
// from ws; LDS assemble; full 128B single-owner rows at original index.
__global__ __launch_bounds__(256) void ingp_finish(
    const vf4* __restrict__ slots, const unsigned* __restrict__ cnt,
    const float* __restrict__ tables,
    const float2* __restrict__ ws,    // [8][S_TOT] float2
    vf4* __restrict__ out,            // [N][8] vf4 rows (original order)
    ResArr ra)
{
    __shared__ float2 a[LVLS][258];
    __shared__ int s_orig[256];
    int base = blockIdx.x * 256;
    int t = threadIdx.x;
    int sidx = base + t;              // < S_TOT exact (3328 blocks)

    bool valid = slot_valid(cnt, sidx);
    float px = -1.0f, py = -1.0f, pz = -1.0f;   // invalid -> cell(0,0,0),
    int orig = -1;                               // lookups broadcast/merged
    if (valid) {
        vf4 v4 = slots[sidx];
        px = v4.x; py = v4.y; pz = v4.z;
        orig = __float_as_int(v4.w);
    }
    s_orig[t] = orig;
    float x = (px + 1.0f) * 0.5f;
    float y = (py + 1.0f) * 0.5f;
    float z = (pz + 1.0f) * 0.5f;

    #pragma unroll
    for (int l = 0; l < 8; ++l) {
        const float2* __restrict__ tab = (const float2*)tables + (size_t)l * TBL;
        float f0, f1;
        level_gather(tab, ra.r[l], x, y, z, f0, f1);
        a[l][t] = make_float2(f0, f1);
    }
    #pragma unroll
    for (int l = 8; l < LVLS; ++l) {
        vf2 w = __builtin_nontemporal_load(
            (const vf2*)(ws + (size_t)(l - 8) * S_TOT + sidx));
        a[l][t] = make_float2(w.x, w.y);
    }
    __syncthreads();

    int j = t & 7;
    int pl = t >> 3;
    #pragma unroll
    for (int it = 0; it < 8; ++it) {
        int pt = pl + it * 32;
        int og = s_orig[pt];
        if (og >= 0) {
            float2 u = a[2 * j][pt];
            float2 v = a[2 * j + 1][pt];
            vf4 o; o.x = u.x; o.y = u.y; o.z = v.x; o.w = v.y;
            // 8 consecutive lanes cover one 128B row -> full-line stores.
            __builtin_nontemporal_store(o, (vf4*)(out + (size_t)og * 8 + j));
        }
    }
}

// Fallback (no usable ws): unsorted single-kernel path.
__global__ __launch_bounds__(256) void ingp_fused_raw(
    const float* __restrict__ pts,
    const float* __restrict__ tables,
    vf4* __restrict__ out, ResArr ra, int npts)
{
    int i = blockIdx.x * 256 + threadIdx.x;
    if (i >= npts) return;
    encode_point_direct(tables, ra,
                        pts[i * 3 + 0], pts[i * 3 + 1], pts[i * 3 + 2],
                        out + (size_t)i * 8);
}

extern "C" void kernel_launch(void* const* d_in, const int* in_sizes, int n_in,
                              void* d_out, int out_size, void* d_ws, size_t ws_size,
                              hipStream_t stream) {
    const float* pts    = (const float*)d_in[0];
    const float* tables = (const float*)d_in[1];
    int npts = in_sizes[0] / 3;

    // numpy-bitwise RES: GROWTH = exp((log(2048)-log(16))/15); floor(16*G**l)
    ResArr ra;
    double growth = exp((log(2048.0) - log(16.0)) / 15.0);
    for (int l = 0; l < LVLS; ++l)
        ra.r[l] = (float)floor(16.0 * pow(growth, (double)l));

    int pgrid = (npts + 255) / 256;

    // ws layout: [ws fine: 8*S_TOT float2][slots: S_TOT vf4][cnt: NBINS+1 u32]
    size_t fine_bytes = 8ull * S_TOT * sizeof(float2);        // ~54.5 MB
    size_t slot_bytes = (size_t)S_TOT * sizeof(vf4);          // ~13.6 MB
    size_t cnt_bytes  = (NBINS + 1) * sizeof(unsigned);       //  128 KB
    size_t need = fine_bytes + slot_bytes + cnt_bytes;        // ~68.3 MB

    if (ws_size >= need) {
        char* w = (char*)d_ws;
        float2*   wsf   = (float2*)w;        w += fine_bytes;
        vf4*      slots = (vf4*)w;           w += slot_bytes;
        unsigned* cnt   = (unsigned*)w;

        hipMemsetAsync(cnt, 0, cnt_bytes, stream);
        hipLaunchKernelGGL(ingp_scatter1, dim3(pgrid), dim3(256), 0, stream,
                           pts, cnt, slots, tables, (vf4*)d_out, ra, npts);
        hipLaunchKernelGGL(ingp_fine,
                           dim3(8 * (S_TOT / SLOTS_PER_FINE_BLOCK)), dim3(256),
                           0, stream, slots, cnt, tables, wsf, ra);
        hipLaunchKernelGGL(ingp_finish, dim3(S_TOT / 256), dim3(256), 0, stream,
                           slots, cnt, tables, wsf, (vf4*)d_out, ra);
    } else {
        hipLaunchKernelGGL(ingp_fused_raw, dim3(pgrid), dim3(256), 0, stream,
                           pts, tables, (vf4*)d_out, ra, npts);
    }
}